// Round 3
// baseline (335.116 us; speedup 1.0000x reference)
//
#include <hip/hip_runtime.h>
#include <hip/hip_bf16.h>
#include <stdint.h>

// Problem constants (from reference)
#define B_  32
#define T_  1024
#define C_  512
#define H_  1024
#define MAXF_ 2048
#define SCALE_ 32.0f   // sqrt(1024)

// Tiling
#define BM 128
#define BN 128
#define BK 32
#define ROWE 32              // bf16 elems per LDS row (64 B); XOR swizzle for banks
#define NSTEP (C_ / BK)      // 16

#define AELEMS (B_ * T_ * C_)   // 16,777,216
#define WELEMS (B_ * H_ * C_)   // 16,777,216
#define WS_NEEDED ((size_t)(AELEMS + WELEMS) * 2)  // 64 MiB bf16

typedef __attribute__((ext_vector_type(8))) short frag_ab;   // 8 bf16 (4 VGPRs)
typedef __attribute__((ext_vector_type(4))) float frag_cd;   // 4 fp32

// RNE float -> bf16 (finite inputs)
__device__ __forceinline__ unsigned short f2bf(float f) {
    union { float f; uint32_t u; } v; v.f = f;
    uint32_t u = v.u;
    return (unsigned short)((u + 0x7FFFu + ((u >> 16) & 1u)) >> 16);
}

__device__ __forceinline__ void gl_lds16(const void* g, void* l) {
    __builtin_amdgcn_global_load_lds(
        (const __attribute__((address_space(1))) unsigned int*)g,
        (__attribute__((address_space(3))) unsigned int*)l, 16, 0, 0);
}

// ---------------------------------------------------------------------------
// Pass 1: fp32 -> bf16 convert + date gather. One element converted ONCE,
// fully coalesced (32 B read, 16 B write per thread). Pure streaming.
// ---------------------------------------------------------------------------
__global__ __launch_bounds__(256)
void cvt_kernel(const float* __restrict__ features,
                const int*   __restrict__ date_idx,
                const float* __restrict__ spikes,
                unsigned short* __restrict__ Ap,   // [B,T,C] bf16
                unsigned short* __restrict__ Wp)   // [B,H,C] bf16
{
    const int u = blockIdx.x * 256 + threadIdx.x;  // one 8-elem unit
    const int NF = AELEMS / 8;                     // 2,097,152 feature units
    const float* src;
    unsigned short* dst;
    if (u < NF) {
        src = features + (size_t)u * 8;
        dst = Ap + (size_t)u * 8;
    } else {
        int v = u - NF;
        int b = v >> 16;                           // 65536 units per sample
        int off = (v & 65535) * 8;
        src = spikes + (size_t)date_idx[b] * (H_ * C_) + off;
        dst = Wp + (size_t)b * (H_ * C_) + off;
    }
    float4 f0 = ((const float4*)src)[0];
    float4 f1 = ((const float4*)src)[1];
    union { unsigned short us[8]; uint4 v4; } p;
    p.us[0] = f2bf(f0.x); p.us[1] = f2bf(f0.y); p.us[2] = f2bf(f0.z); p.us[3] = f2bf(f0.w);
    p.us[4] = f2bf(f1.x); p.us[5] = f2bf(f1.y); p.us[6] = f2bf(f1.z); p.us[7] = f2bf(f1.w);
    *(uint4*)dst = p.v4;
}

// ---------------------------------------------------------------------------
// Pass 2: bf16 GEMM, m97 structure. global_load_lds(16B) staging (no VGPR
// round-trip, no staging VALU), double-buffered LDS, 1 barrier/step.
// Bank swizzle is baked into the GLOBAL source address: the DMA writes LDS
// lane-ordered, so reading global group (grp ^ swz(row)) lands the LDS image
// in round-2's measured-0-conflict layout.
// ---------------------------------------------------------------------------
__global__ __launch_bounds__(256, 4)
void gemm_kernel(const unsigned short* __restrict__ Ap,  // [B,T,C] bf16
                 const unsigned short* __restrict__ Wp,  // [B,H,C] bf16
                 const int*   __restrict__ ts,           // [B,T]
                 const int*   __restrict__ date_idx,     // [B]
                 const float* __restrict__ spikes_bias,  // [N_DATES]
                 const float* __restrict__ pos,          // [MAX_F,H]
                 float*       __restrict__ out)          // [B,T,H]
{
    const int tid = threadIdx.x;
    const int bid = blockIdx.x;

    // XCD-clustered mapping (round 2, verified: FETCH 318->139 MB).
    const int xcd   = bid & 7;
    const int local = bid >> 3;
    const int b     = ((local >> 6) << 3) + xcd;
    const int tile  = local & 63;
    const int t0 = (tile >> 3) * BM;
    const int h0 = (tile & 7) * BN;

    const float bias = spikes_bias[date_idx[b]];
    const unsigned short* A = Ap + ((size_t)b * T_ + t0) * C_;
    const unsigned short* W = Wp + ((size_t)b * H_ + h0) * C_;

    __shared__ __align__(16) unsigned short ldsA[2][BM * ROWE]; // 8 KB each
    __shared__ __align__(16) unsigned short ldsB[2][BM * ROWE];
    __shared__ int lds_ts[BM];

    if (tid < BM) lds_ts[tid] = ts[b * T_ + t0 + tid];

    // Staging coords: 512 16B-groups per matrix per step; thread handles
    // groups tid and tid+256 (per wave: base + lane*16 — DMA-legal).
    const int r0 = tid >> 2,          g0 = tid & 3;
    const int r1 = (tid + 256) >> 2,  g1 = tid & 3;
    const int p0 = ((g0 ^ ((r0 >> 1) & 3)) * 8);   // swizzled elem offset in row
    const int p1 = ((g1 ^ ((r1 >> 1) & 3)) * 8);
    const unsigned short* sA0 = A + (size_t)r0 * C_ + p0;
    const unsigned short* sA1 = A + (size_t)r1 * C_ + p1;
    const unsigned short* sB0 = W + (size_t)r0 * C_ + p0;
    const unsigned short* sB1 = W + (size_t)r1 * C_ + p1;
    const int d0 = tid * 8;            // LDS elem offset (byte = tid*16)
    const int d1 = (tid + 256) * 8;

    auto issue = [&](int buf, int ks) {
        const int ko = ks * BK;
        gl_lds16(sA0 + ko, &ldsA[buf][d0]);
        gl_lds16(sA1 + ko, &ldsA[buf][d1]);
        gl_lds16(sB0 + ko, &ldsB[buf][d0]);
        gl_lds16(sB1 + ko, &ldsB[buf][d1]);
    };

    issue(0, 0);

    // Wave/lane decode + hoisted frag offsets
    const int wave = tid >> 6;
    const int lane = tid & 63;
    const int quad = lane >> 4;
    const int m_   = lane & 15;
    const int wm = (wave >> 1) * 64;
    const int wn = (wave & 1) * 64;

    int offA[4], offB[4];
#pragma unroll
    for (int i = 0; i < 4; ++i) {
        int ra = wm + i * 16 + m_;
        int rb = wn + i * 16 + m_;
        offA[i] = ra * ROWE + ((quad ^ ((ra >> 1) & 3)) * 8);
        offB[i] = rb * ROWE + ((quad ^ ((rb >> 1) & 3)) * 8);
    }

    frag_cd acc[4][4] = {};
    __syncthreads();

    for (int ks = 0; ks < NSTEP; ++ks) {
        const int buf = ks & 1;
        if (ks + 1 < NSTEP) issue(buf ^ 1, ks + 1);

        frag_ab afrag[4], bfrag[4];
#pragma unroll
        for (int i = 0; i < 4; ++i) {
            afrag[i] = *(const frag_ab*)&ldsA[buf][offA[i]];
            bfrag[i] = *(const frag_ab*)&ldsB[buf][offB[i]];
        }
#pragma unroll
        for (int mi = 0; mi < 4; ++mi)
#pragma unroll
            for (int ni = 0; ni < 4; ++ni)
                acc[mi][ni] = __builtin_amdgcn_mfma_f32_16x16x32_bf16(
                    afrag[mi], bfrag[ni], acc[mi][ni], 0, 0, 0);

        __syncthreads();
    }

    // Epilogue: acc*SCALE + bias + pos[ts[t]][h]
    // C/D layout (m89-verified): col = lane&15 (h), row = quad*4 + reg (t)
#pragma unroll
    for (int mi = 0; mi < 4; ++mi) {
#pragma unroll
        for (int r = 0; r < 4; ++r) {
            int trow = wm + mi * 16 + quad * 4 + r;
            int tsv  = lds_ts[trow];
            const float* prow = pos + (size_t)tsv * H_ + h0;
            size_t orow = ((size_t)b * T_ + (t0 + trow)) * (size_t)H_ + h0;
#pragma unroll
            for (int ni = 0; ni < 4; ++ni) {
                int col = wn + ni * 16 + m_;
                out[orow + col] = acc[mi][ni][r] * SCALE_ + bias + prow[col];
            }
        }
    }
}

// ---------------------------------------------------------------------------
// Fallback (ws too small): round-2 single-pass kernel, verified correct.
// ---------------------------------------------------------------------------
__device__ __forceinline__ void cvt4_store(unsigned short* dst, float4 v) {
    union { unsigned short u[4]; uint2 d; } p;
    p.u[0] = f2bf(v.x); p.u[1] = f2bf(v.y); p.u[2] = f2bf(v.z); p.u[3] = f2bf(v.w);
    *(uint2*)dst = p.d;
}

__global__ __launch_bounds__(256, 4)
void fused_kernel(const float* __restrict__ features, const int* __restrict__ ts,
                  const int* __restrict__ date_idx, const float* __restrict__ spikes,
                  const float* __restrict__ spikes_bias, const float* __restrict__ pos,
                  float* __restrict__ out)
{
    const int tid = threadIdx.x;
    const int bid = blockIdx.x;
    const int xcd   = bid & 7;
    const int local = bid >> 3;
    const int b     = ((local >> 6) << 3) + xcd;
    const int tile  = local & 63;
    const int t0 = (tile >> 3) * BM;
    const int h0 = (tile & 7) * BN;

    const int   date = date_idx[b];
    const float bias = spikes_bias[date];
    const float* A = features + ((size_t)b * T_ + t0) * C_;
    const float* W = spikes   + ((size_t)date * H_ + h0) * C_;

    __shared__ __align__(16) unsigned short ldsA[2][BM * ROWE];
    __shared__ __align__(16) unsigned short ldsB[2][BM * ROWE];
    __shared__ int lds_ts[BM];
    if (tid < BM) lds_ts[tid] = ts[b * T_ + t0 + tid];

    float4 pfA[4], pfB[4];
    auto gload = [&](const float* __restrict__ base, int i, int k0) -> float4 {
        int g = i * 256 + tid;
        int row = g >> 3, k4 = g & 7;
        return *(const float4*)(base + (size_t)row * C_ + k0 + k4 * 4);
    };
    auto stage = [&](int buf) {
#pragma unroll
        for (int i = 0; i < 4; ++i) {
            int g = i * 256 + tid;
            int row = g >> 3, j = g & 7;
            int s = (j >> 1) ^ ((row >> 1) & 3);
            int off = row * ROWE + s * 8 + (j & 1) * 4;
            cvt4_store(&ldsA[buf][off], pfA[i]);
            cvt4_store(&ldsB[buf][off], pfB[i]);
        }
    };

#pragma unroll
    for (int i = 0; i < 4; ++i) { pfA[i] = gload(A, i, 0); pfB[i] = gload(W, i, 0); }
    stage(0);
    __syncthreads();

    const int wave = tid >> 6, lane = tid & 63;
    const int quad = lane >> 4, m_ = lane & 15;
    const int wm = (wave >> 1) * 64, wn = (wave & 1) * 64;
    frag_cd acc[4][4] = {};

    for (int ks = 0; ks < NSTEP; ++ks) {
        const int buf = ks & 1;
        if (ks + 1 < NSTEP) {
            const int k0 = (ks + 1) * BK;
#pragma unroll
            for (int i = 0; i < 4; ++i) { pfA[i] = gload(A, i, k0); pfB[i] = gload(W, i, k0); }
        }
        frag_ab afrag[4], bfrag[4];
#pragma unroll
        for (int mi = 0; mi < 4; ++mi) {
            int row = wm + mi * 16 + m_;
            afrag[mi] = *(const frag_ab*)&ldsA[buf][row * ROWE + (((quad ^ ((row >> 1) & 3))) * 8)];
        }
#pragma unroll
        for (int ni = 0; ni < 4; ++ni) {
            int row = wn + ni * 16 + m_;
            bfrag[ni] = *(const frag_ab*)&ldsB[buf][row * ROWE + (((quad ^ ((row >> 1) & 3))) * 8)];
        }
#pragma unroll
        for (int mi = 0; mi < 4; ++mi)
#pragma unroll
            for (int ni = 0; ni < 4; ++ni)
                acc[mi][ni] = __builtin_amdgcn_mfma_f32_16x16x32_bf16(
                    afrag[mi], bfrag[ni], acc[mi][ni], 0, 0, 0);
        if (ks + 1 < NSTEP) stage((ks + 1) & 1);
        __syncthreads();
    }

#pragma unroll
    for (int mi = 0; mi < 4; ++mi) {
#pragma unroll
        for (int r = 0; r < 4; ++r) {
            int trow = wm + mi * 16 + quad * 4 + r;
            int tsv  = lds_ts[trow];
            const float* prow = pos + (size_t)tsv * H_ + h0;
            size_t orow = ((size_t)b * T_ + (t0 + trow)) * (size_t)H_ + h0;
#pragma unroll
            for (int ni = 0; ni < 4; ++ni) {
                int col = wn + ni * 16 + m_;
                out[orow + col] = acc[mi][ni][r] * SCALE_ + bias + prow[col];
            }
        }
    }
}

extern "C" void kernel_launch(void* const* d_in, const int* in_sizes, int n_in,
                              void* d_out, int out_size, void* d_ws, size_t ws_size,
                              hipStream_t stream) {
    const float* features  = (const float*)d_in[0];
    const int*   ts        = (const int*)d_in[1];
    const int*   date_idx  = (const int*)d_in[2];
    const float* spikes    = (const float*)d_in[3];
    const float* sbias     = (const float*)d_in[4];
    const float* pos       = (const float*)d_in[5];
    float*       out       = (float*)d_out;

    const dim3 ggrid(B_ * (T_ / BM) * (H_ / BN));   // 2048

    if (ws_size >= WS_NEEDED) {
        unsigned short* Ap = (unsigned short*)d_ws;
        unsigned short* Wp = Ap + AELEMS;
        cvt_kernel<<<(AELEMS + WELEMS) / 8 / 256, 256, 0, stream>>>(
            features, date_idx, spikes, Ap, Wp);
        gemm_kernel<<<ggrid, 256, 0, stream>>>(Ap, Wp, ts, date_idx, sbias, pos, out);
    } else {
        fused_kernel<<<ggrid, 256, 0, stream>>>(
            features, ts, date_idx, spikes, sbias, pos, out);
    }
}